// Round 8
// baseline (347.093 us; speedup 1.0000x reference)
//
#include <hip/hip_runtime.h>
#include <math.h>

// MADE autoregressive sampler, incremental-by-degree, v7: wave-autonomous.
// B=8192, D=64, CTX=256, H=512. Units sorted by degree (mh = h%63+1).
// v7: each wave owns 2 batch rows end-to-end; lane l owns sorted units
// q in [8l, 8l+8) (a1/a2 in regs), output cols {l, l+64}, and z/mu/sc for
// col l. All communication is intra-wave (shfl + per-wave LDS, program-order,
// NO __syncthreads in the 64-step loop). v6's 3-barrier/step convoy was ~60%
// of wall; this removes it. Weight layouts identical to v6 (zero-padded
// per-step blocks) so masked-out contributions are multiplications by zero.
// (Round 8 resubmit: round-7 bench died to a container infra flake, not the
// kernel -- source is byte-identical to round 7.)

#define Bn 8192
#define Dn 64
#define CTXn 256
#define Hn 512
#define On 128

#define W2G_SZ (64 * 9 * 512)   // 294912
#define WOG_SZ (64 * 9 * 128)   //  73728
#define WCP_SZ (CTXn * Hn)      // 131072
#define W1C_SZ (Dn * Hn)        //  32768

// S_of(k) = # units with degree < k. Degrees 1..8 have 9 units, 9..63 have 8.
// Degree-k units occupy [S_of(k), S_of(k+1)). S_of(64)=512.
__device__ __forceinline__ int S_of(int k) {
  if (k <= 0) return 0;
  if (k <= 9) return 9 * (k - 1);
  return 72 + 8 * (k - 9);
}

// sorted index p -> original hidden unit h, and its degree k.
__device__ __forceinline__ int perm_of(int p, int* degout) {
  int k, t;
  if (p < 72) { k = p / 9 + 1; t = p - (k - 1) * 9; }
  else        { int pp = p - 72; k = pp / 8 + 9; t = pp - (k - 9) * 8; }
  *degout = k;
  return (k - 1) + 63 * t;
}

// ---------------- prep: padded/masked weight blocks into ws (same as v6) ----
__global__ void prep_kernel(const float* __restrict__ W1, const float* __restrict__ Wc,
                            const float* __restrict__ W2, const float* __restrict__ Wo,
                            float* __restrict__ W2g, float* __restrict__ Wog,
                            float* __restrict__ WcpT, float* __restrict__ W1c) {
  int idx = blockIdx.x * 256 + threadIdx.x;
  if (idx < W2G_SZ) {
    int i = idx / 4608, rem = idx - i * 4608;
    int p = rem >> 9, q = rem & 511;
    int base = S_of(i + 1), c = S_of(i + 2) - base;   // degree-(i+1) group
    int dq; int hq = perm_of(q, &dq);
    float v = 0.f;
    if (p < c && dq >= i + 1) {            // M2: deg_out >= deg_in (= i+1)
      int dp; int hp = perm_of(base + p, &dp);
      v = W2[hq * Hn + hp];
    }
    W2g[idx] = v;
  } else if (idx < W2G_SZ + WOG_SZ) {
    int jj = idx - W2G_SZ;
    int i = jj / 1152, rem = jj - i * 1152;
    int p = rem >> 7, o = rem & 127;
    int base = S_of(i + 1), c = S_of(i + 2) - base;
    float v = 0.f;
    if (p < c && (o & 63) >= i + 1) {      // Mo: m_o = (o&63)+1 > mh = i+1
      int dp; int hp = perm_of(base + p, &dp);
      v = Wo[o * Hn + hp];
    }
    Wog[jj] = v;
  } else if (idx < W2G_SZ + WOG_SZ + WCP_SZ) {
    int jj = idx - (W2G_SZ + WOG_SZ);
    int cc = jj >> 9, q = jj & 511;
    int dq; int hq = perm_of(q, &dq);
    WcpT[jj] = Wc[hq * CTXn + cc];
  } else if (idx < W2G_SZ + WOG_SZ + WCP_SZ + W1C_SZ) {
    int jj = idx - (W2G_SZ + WOG_SZ + WCP_SZ);
    int i = jj >> 9, q = jj & 511;
    int dq; int hq = perm_of(q, &dq);
    W1c[jj] = (dq >= i + 1) ? W1[hq * Dn + i] : 0.f;   // M1 incl. diagonal
  }
}

// ---------------- main fused kernel ------------------------------------------
__global__ __launch_bounds__(256, 2)
void made_wave_kernel(
    const float* __restrict__ context, const float* __restrict__ WcpT,
    const float* __restrict__ b1,
    const float* __restrict__ W2g, const float* __restrict__ W1c,
    const float* __restrict__ Wog, const float* __restrict__ b2,
    const float* __restrict__ bo, const float* __restrict__ eps,
    float* __restrict__ out) {
  __shared__ __align__(16) float ctxR[8][264];    // GEMM staging (prologue)
  __shared__ __align__(16) float trL[8][512];     // a1 transpose (prologue)
  __shared__ __align__(16) float h1b[4][9][2];    // per-wave group-h1 bcast
  __shared__ __align__(16) float h2b[4][9][2];    // per-wave group-h2 bcast

  int t = threadIdx.x;
  int b0 = blockIdx.x * 8;
  int w = t >> 6, l = t & 63;

  // ================= prologue: ctx GEMM (q-split, 8-row reuse) =============
  #pragma unroll
  for (int r = 0; r < 8; ++r)
    ctxR[r][t] = context[(b0 + r) * CTXn + t];            // coalesced
  __syncthreads();

  {
    int q0 = t, q1 = t + 256;
    int d0, d1; int h0 = perm_of(q0, &d0); int h1 = perm_of(q1, &d1);
    float acc0[8], acc1[8];
    float bias0 = b1[h0], bias1 = b1[h1];
    #pragma unroll
    for (int r = 0; r < 8; ++r) { acc0[r] = bias0; acc1[r] = bias1; }
    const float* wc = WcpT;
    #pragma clang loop unroll(disable)
    for (int c4 = 0; c4 < CTXn / 4; ++c4) {
      float xr[8][4];
      #pragma unroll
      for (int r = 0; r < 8; ++r) {
        float4 x = *(const float4*)&ctxR[r][4 * c4];
        xr[r][0] = x.x; xr[r][1] = x.y; xr[r][2] = x.z; xr[r][3] = x.w;
      }
      #pragma unroll
      for (int k = 0; k < 4; ++k) {
        float w0 = wc[q0];
        float w1 = wc[q1];
        #pragma unroll
        for (int r = 0; r < 8; ++r) {
          acc0[r] = fmaf(xr[r][k], w0, acc0[r]);
          acc1[r] = fmaf(xr[r][k], w1, acc1[r]);
        }
        wc += Hn;
      }
    }
    // transpose a1 through LDS: [r][q]
    #pragma unroll
    for (int r = 0; r < 8; ++r) { trL[r][q0] = acc0[r]; trL[r][q1] = acc1[r]; }
  }
  __syncthreads();

  // ================= wave-split reload: lane l owns q in [8l, 8l+8) ========
  int r0 = 2 * w, r1 = 2 * w + 1;      // block-local rows of this wave
  float2 a1v[8], a2v[8];
  int f[8];                            // finalize step of each owned unit
  {
    float4 xa = *(const float4*)&trL[r0][8 * l];
    float4 xb = *(const float4*)&trL[r0][8 * l + 4];
    float4 ya = *(const float4*)&trL[r1][8 * l];
    float4 yb = *(const float4*)&trL[r1][8 * l + 4];
    a1v[0] = make_float2(xa.x, ya.x); a1v[1] = make_float2(xa.y, ya.y);
    a1v[2] = make_float2(xa.z, ya.z); a1v[3] = make_float2(xa.w, ya.w);
    a1v[4] = make_float2(xb.x, yb.x); a1v[5] = make_float2(xb.y, yb.y);
    a1v[6] = make_float2(xb.z, yb.z); a1v[7] = make_float2(xb.w, yb.w);
  }
  #pragma unroll
  for (int m = 0; m < 8; ++m) {
    int dd; int hh = perm_of(8 * l + m, &dd);
    float bb = b2[hh];
    a2v[m] = make_float2(bb, bb);
    f[m] = dd - 1;
  }
  int fmin = f[0], fmax = f[7];

  float oc00 = bo[l], oc01 = bo[l + 64];   // row r0: cols l, l+64
  float oc10 = oc00,  oc11 = oc01;         // row r1
  float ez0 = eps[(b0 + r0) * Dn + l];     // eps at col l (used at step l)
  float ez1 = eps[(b0 + r1) * Dn + l];
  float zv0 = 0.f, zv1 = 0.f, muv0 = 0.f, muv1 = 0.f, scv0 = 0.f, scv1 = 0.f;

  // ================= barrier-free sequential loop ==========================
  #pragma clang loop unroll(disable)
  for (int i = 0; i < Dn; ++i) {
    // E: lane i's cols (i, 64+i) are final (oacc through step i-1, in-order)
    if (l == i) {
      muv0 = oc00; muv1 = oc10;
      float pre0 = oc01, pre1 = oc11;
      scv0 = fmaxf(pre0, 0.f) + __logf(1.f + __expf(-fabsf(pre0)));
      scv1 = fmaxf(pre1, 0.f) + __logf(1.f + __expf(-fabsf(pre1)));
      zv0 = muv0 + scv0 * ez0;
      zv1 = muv1 + scv1 * ez1;
    }
    float z0 = __shfl(zv0, i);             // intra-wave broadcast, no barrier
    float z1 = __shfl(zv1, i);
    int sb = (i <= 8) ? 9 * i : 8 * i + 8; // S_of(i+1): base of group i

    // FA: a1 += z_i * W1c[i][q] (zero-masked for finalized q, incl diagonal);
    // group-i units (f[m]==i) finalize -> relu -> per-wave LDS broadcast
    if (fmax >= i) {
      const float* w1r = W1c + i * Hn + 8 * l;
      float4 wa = *(const float4*)w1r;
      float4 wb = *(const float4*)(w1r + 4);
      float wm[8] = {wa.x, wa.y, wa.z, wa.w, wb.x, wb.y, wb.z, wb.w};
      #pragma unroll
      for (int m = 0; m < 8; ++m) {
        a1v[m].x = fmaf(wm[m], z0, a1v[m].x);
        a1v[m].y = fmaf(wm[m], z1, a1v[m].y);
      }
      if (i >= fmin) {
        #pragma unroll
        for (int m = 0; m < 8; ++m) {
          if (f[m] == i) {
            int p = 8 * l + m - sb;
            *(float2*)&h1b[w][p][0] =
                make_float2(fmaxf(a1v[m].x, 0.f), fmaxf(a1v[m].y, 0.f));
          }
        }
      }
    }
    // BC: a2 += W2g[i] . h1 (same-wave ds_write->ds_read, program order);
    // group-i units finalize -> relu -> h2 broadcast
    if (fmax >= i) {
      const float* w2b = W2g + (size_t)i * 4608 + 8 * l;
      #pragma unroll
      for (int p = 0; p < 9; ++p) {
        float4 wa = *(const float4*)(w2b + p * Hn);
        float4 wb = *(const float4*)(w2b + p * Hn + 4);
        float2 h = *(const float2*)&h1b[w][p][0];   // wave-uniform: broadcast
        float wm[8] = {wa.x, wa.y, wa.z, wa.w, wb.x, wb.y, wb.z, wb.w};
        #pragma unroll
        for (int m = 0; m < 8; ++m) {
          a2v[m].x = fmaf(wm[m], h.x, a2v[m].x);
          a2v[m].y = fmaf(wm[m], h.y, a2v[m].y);
        }
      }
      if (i >= fmin) {
        #pragma unroll
        for (int m = 0; m < 8; ++m) {
          if (f[m] == i) {
            int p = 8 * l + m - sb;
            *(float2*)&h2b[w][p][0] =
                make_float2(fmaxf(a2v[m].x, 0.f), fmaxf(a2v[m].y, 0.f));
          }
        }
      }
    }
    // D: oacc += h2 . Wog[i] for this lane's cols (zero-masked for o<=i)
    if (l > i) {
      const float* wo = Wog + (size_t)i * 1152;
      #pragma unroll
      for (int p = 0; p < 9; ++p) {
        float w0 = wo[p * On + l];               // coalesced over l
        float w1 = wo[p * On + 64 + l];
        float2 h = *(const float2*)&h2b[w][p][0];
        oc00 = fmaf(h.x, w0, oc00); oc01 = fmaf(h.x, w1, oc01);
        oc10 = fmaf(h.y, w0, oc10); oc11 = fmaf(h.y, w1, oc11);
      }
    }
  }

  // ================= epilogue: lane l writes col l of z, mu, scale =========
  out[(b0 + r0) * Dn + l] = zv0;
  out[(b0 + r1) * Dn + l] = zv1;
  out[Bn * Dn + (b0 + r0) * Dn + l] = muv0;
  out[Bn * Dn + (b0 + r1) * Dn + l] = muv1;
  out[2 * Bn * Dn + (b0 + r0) * Dn + l] = scv0;
  out[2 * Bn * Dn + (b0 + r1) * Dn + l] = scv1;
}

extern "C" void kernel_launch(void* const* d_in, const int* in_sizes, int n_in,
                              void* d_out, int out_size, void* d_ws, size_t ws_size,
                              hipStream_t stream) {
  const float* context = (const float*)d_in[0];
  const float* eps     = (const float*)d_in[1];
  const float* W1      = (const float*)d_in[2];
  const float* b1      = (const float*)d_in[3];
  const float* Wc      = (const float*)d_in[4];
  const float* W2      = (const float*)d_in[5];
  const float* b2      = (const float*)d_in[6];
  const float* Wo      = (const float*)d_in[7];
  const float* bo      = (const float*)d_in[8];
  float* out = (float*)d_out;

  float* ws   = (float*)d_ws;
  float* W2g  = ws;                 // 294912 floats
  float* Wog  = W2g + W2G_SZ;       //  73728
  float* WcpT = Wog + WOG_SZ;       // 131072
  float* W1c  = WcpT + WCP_SZ;      //  32768
  // total ws use: ~2.1 MB (L2-resident)

  int prep_elems = W2G_SZ + WOG_SZ + WCP_SZ + W1C_SZ;
  prep_kernel<<<(prep_elems + 255) / 256, 256, 0, stream>>>(
      W1, Wc, W2, Wo, W2g, Wog, WcpT, W1c);
  made_wave_kernel<<<Bn / 8, 256, 0, stream>>>(context, WcpT, b1, W2g, W1c,
                                               Wog, b2, bo, eps, out);
}